// Round 6
// baseline (30.209 us; speedup 1.0000x reference)
//
#include <hip/hip_runtime.h>
#include <math.h>

#define NH    16384   // Hadamard size (2^14)
#define NRES  8192
#define NINP  64
#define BATCH 512

// ---------------- LDS swizzle (same family as r5, all patterns rank-3) ----
__device__ __forceinline__ constexpr int gfold(int v) {
    return ((v >> 5) & 7) ^ ((v >> 8) & 7) ^ ((v >> 11) & 7);
}
__device__ __forceinline__ constexpr int physf(int v) {
    return v ^ (gfold(v) << 2);
}

// ---------------- in-register FWHT stages ---------------------------------
template <int S>
__device__ __forceinline__ void stage64(float x[64]) {
#pragma unroll
    for (int i = 0; i < 64; ++i) {
        if (!(i & S)) {
            float a = x[i], b = x[i | S];
            x[i]     = a + b;
            x[i | S] = a - b;
        }
    }
}

// ---------------- cross-lane primitives ------------------------------------
template <int CTRL>
__device__ __forceinline__ float dppf(float v) {
    return __builtin_bit_cast(float,
        __builtin_amdgcn_update_dpp(0, __builtin_bit_cast(int, v), CTRL, 0xF, 0xF, true));
}

// Shuffle-exchange: swap register j-bits with lane bits, pure VALU pipe.
//   j0 <-> l0 : DPP quad_perm xor1 (0xB1)
//   j1 <-> l1 : DPP quad_perm xor2 (0x4E)
//   j2 <-> l4 : v_permlane16_swap_b32  (A.row_odd16 <-> B.row_even16)
//   j3 <-> l5 : v_permlane32_swap_b32  (A.hi32 <-> B.lo32)
__device__ __forceinline__ void shuffle_exchange(float x[64], bool odd0, bool odd1) {
#pragma unroll
    for (int e = 0; e < 64; ++e) if (!(e & 4)) {         // j0 <-> l0
        float A = x[e], B = x[e + 4];
        float dA = dppf<0xB1>(A), dB = dppf<0xB1>(B);
        x[e]     = odd0 ? dB : A;
        x[e + 4] = odd0 ? B  : dA;
    }
#pragma unroll
    for (int e = 0; e < 64; ++e) if (!(e & 8)) {         // j1 <-> l1
        float A = x[e], B = x[e + 8];
        float dA = dppf<0x4E>(A), dB = dppf<0x4E>(B);
        x[e]     = odd1 ? dB : A;
        x[e + 8] = odd1 ? B  : dA;
    }
#pragma unroll
    for (int e = 0; e < 64; ++e) if (!(e & 16))          // j2 <-> l4
        asm("v_permlane16_swap_b32 %0, %1" : "+v"(x[e]), "+v"(x[e + 16]));
#pragma unroll
    for (int e = 0; e < 64; ++e) if (!(e & 32))          // j3 <-> l5
        asm("v_permlane32_swap_b32 %0, %1" : "+v"(x[e]), "+v"(x[e + 32]));
}

// ---------------- LDS exchange helpers -------------------------------------
#define WRX(Q, SH) do { _Pragma("unroll") \
    for (int j = 0; j < 16; ++j) \
        lds4[(unsigned)((Q) ^ physf(j << (SH))) >> 2] = \
            make_float4(x[4*j+0], x[4*j+1], x[4*j+2], x[4*j+3]); } while (0)

#define RDX(Q, SH) do { _Pragma("unroll") \
    for (int j = 0; j < 16; ++j) { \
        float4 v = lds4[(unsigned)((Q) ^ physf(j << (SH))) >> 2]; \
        x[4*j+0] = v.x; x[4*j+1] = v.y; x[4*j+2] = v.z; x[4*j+3] = v.w; } } while (0)

// Layouts (idx bit homes; v=idx{0,1} in-register, j = 4 register bits,
// la={l0,l1}, lb={l4,l5}, lc={l2,l3}, w = wave bits):
//  T_A: j@{2-5}, la@{6,7}, lb@{8,9}, lc@{10,11}, w@{12,13}    off = j<<2
//  T_B: j@{6-9}, la@{2,3}, lb@{4,5}, lc@{10,11}, w@{12,13}    off = j<<6
//  T_C: j@{10-13}, la@{2,3}, lb@{4,5}, lc@{6,7}, w@{8,9}      off = j<<10
//  T_D: j@{2-5},  lc@{6,7}, w@{8,9}, la@{10,11}, lb@{12,13}   off = j<<2
// Plan: P1(T_A: L0 {0-5}) -shuf-> P2(T_B: L0 {6-9}) -LDS-> P3(T_C: L0 {10-13},
// diag1, L1 {0,1,10-13}) -shuf-> P4(T_D: L1 {2-5}) -LDS-> P5(T_B: L1 {6-9},
// diag2, L2 {0,1,6-9}) -shuf-> P6(T_A: L2 {2-5}) -LDS-> P7(T_C: L2 {10-13}, out)

__global__ __launch_bounds__(256, 2) void st_kernel(
    const float* __restrict__ state, const float* __restrict__ inputs,
    const float* __restrict__ bias,  const float* __restrict__ diag,
    float* __restrict__ out)
{
    __shared__ float4 lds4[NH / 4];
    const int t = threadIdx.x;   // 0..255
    const int r = blockIdx.x;    // 0..511
    const int l = t & 63, w = t >> 6;
    const int l01 = l & 3, l23 = (l >> 2) & 3, l45 = (l >> 4) & 3;
    const bool odd0 = (l & 1), odd1 = (l & 2);

    const int bA = (w << 12) | (l23 << 10) | (l45 << 8) | (l01 << 6);
    const int bB = (w << 12) | (l23 << 10) | (l45 << 4) | (l01 << 2);
    const int bC = (w << 8)  | (l23 << 6)  | (l45 << 4) | (l01 << 2);
    const int bD = (l45 << 12) | (l01 << 10) | (w << 8) | (l23 << 6);

    float x[64];

    // ---------- prologue: load in T_A layout (idx = bA + f) ----------
    if (t < 128) {                       // idx13 = w1 = 0 -> state half
        const float* srow = state + (size_t)r * NRES + bA;
        const float* d0   = diag + bA;
#pragma unroll
        for (int j = 0; j < 16; ++j) {
            float4 v = *(const float4*)(srow + 4 * j);
            float4 d = *(const float4*)(d0 + 4 * j);
            x[4*j+0] = 0.9f * v.x * d.x; x[4*j+1] = 0.9f * v.y * d.y;
            x[4*j+2] = 0.9f * v.z * d.z; x[4*j+3] = 0.9f * v.w * d.w;
        }
    } else if (t == 128) {               // bA = 8192 -> inputs
        const float* irow = inputs + r * NINP;
        const float* d0   = diag + NRES;
#pragma unroll
        for (int j = 0; j < 16; ++j) {
            float4 v = *(const float4*)(irow + 4 * j);
            float4 d = *(const float4*)(d0 + 4 * j);
            x[4*j+0] = 0.4f * v.x * d.x; x[4*j+1] = 0.4f * v.y * d.y;
            x[4*j+2] = 0.4f * v.z * d.z; x[4*j+3] = 0.4f * v.w * d.w;
        }
    } else {
#pragma unroll
        for (int e = 0; e < 64; ++e) x[e] = 0.f;
    }

    // ---------- P1 (T_A): layer0 bits 0-5 ----------
    stage64<1>(x); stage64<2>(x); stage64<4>(x);
    stage64<8>(x); stage64<16>(x); stage64<32>(x);

    // ---------- E1 (shuffle): T_A -> T_B ----------
    shuffle_exchange(x, odd0, odd1);
    stage64<4>(x); stage64<8>(x); stage64<16>(x); stage64<32>(x);   // L0 6-9

    // ---------- E2 (LDS): T_B -> T_C ----------
    { const int Q = physf(bB); WRX(Q, 6); }
    __syncthreads();
    { const int Q = physf(bC); RDX(Q, 10); }

    // prefetch diag1 (T_C: idx = bC | j<<10 | v)
    float4 pf[16];
    {
        const float* d1 = diag + NH + bC;
#pragma unroll
        for (int j = 0; j < 16; ++j) pf[j] = *(const float4*)(d1 + (j << 10));
    }
    stage64<4>(x); stage64<8>(x); stage64<16>(x); stage64<32>(x);   // L0 10-13
#pragma unroll
    for (int j = 0; j < 16; ++j) {                                   // diag1
        x[4*j+0] *= pf[j].x; x[4*j+1] *= pf[j].y;
        x[4*j+2] *= pf[j].z; x[4*j+3] *= pf[j].w;
    }
    stage64<1>(x); stage64<2>(x);                                    // L1 0-1
    stage64<4>(x); stage64<8>(x); stage64<16>(x); stage64<32>(x);   // L1 10-13

    // ---------- E3 (shuffle): T_C -> T_D ----------
    shuffle_exchange(x, odd0, odd1);
    stage64<4>(x); stage64<8>(x); stage64<16>(x); stage64<32>(x);   // L1 2-5

    // ---------- E4 (LDS): T_D -> T_B ----------
    __syncthreads();                     // protect buffer from E2 reads
    { const int Q = physf(bD); WRX(Q, 2); }
    __syncthreads();
    { const int Q = physf(bB); RDX(Q, 6); }

    // prefetch diag2 (T_B: idx = bB | j<<6 | v)
    {
        const float* d2 = diag + 2 * NH + bB;
#pragma unroll
        for (int j = 0; j < 16; ++j) pf[j] = *(const float4*)(d2 + (j << 6));
    }
    stage64<4>(x); stage64<8>(x); stage64<16>(x); stage64<32>(x);   // L1 6-9
#pragma unroll
    for (int j = 0; j < 16; ++j) {                                   // diag2
        x[4*j+0] *= pf[j].x; x[4*j+1] *= pf[j].y;
        x[4*j+2] *= pf[j].z; x[4*j+3] *= pf[j].w;
    }
    stage64<1>(x); stage64<2>(x);                                    // L2 0-1
    stage64<4>(x); stage64<8>(x); stage64<16>(x); stage64<32>(x);   // L2 6-9

    // ---------- E5 (shuffle): T_B -> T_A ----------
    shuffle_exchange(x, odd0, odd1);
    stage64<4>(x); stage64<8>(x); stage64<16>(x); stage64<32>(x);   // L2 2-5

    // ---------- E6 (LDS): T_A -> T_C ----------
    __syncthreads();                     // protect buffer from E4 reads
    { const int Q = physf(bA); WRX(Q, 2); }
    __syncthreads();
    { const int Q = physf(bC); RDX(Q, 10); }

    // prefetch bias (output half j<8: idx = bC | j<<10 | v)
    float4 bv[8];
#pragma unroll
    for (int j = 0; j < 8; ++j) bv[j] = *(const float4*)(bias + bC + (j << 10));

    stage64<4>(x); stage64<8>(x); stage64<16>(x); stage64<32>(x);   // L2 10-13

    // ---------- epilogue: idx13 = j3 = 0 -> j<8 ----------
    {
        float* orow = out + (size_t)r * NRES;
        const float inv = 1.0f / (float)NH;
#pragma unroll
        for (int j = 0; j < 8; ++j) {
            float4 o;
            o.x = erff(x[4*j+0] * inv + bv[j].x);
            o.y = erff(x[4*j+1] * inv + bv[j].y);
            o.z = erff(x[4*j+2] * inv + bv[j].z);
            o.w = erff(x[4*j+3] * inv + bv[j].w);
            *(float4*)(orow + bC + (j << 10)) = o;
        }
    }
}

extern "C" void kernel_launch(void* const* d_in, const int* in_sizes, int n_in,
                              void* d_out, int out_size, void* d_ws, size_t ws_size,
                              hipStream_t stream) {
    (void)in_sizes; (void)n_in; (void)out_size; (void)d_ws; (void)ws_size;
    const float* state  = (const float*)d_in[0];
    const float* inputs = (const float*)d_in[1];
    const float* bias   = (const float*)d_in[2];
    const float* diag   = (const float*)d_in[3];
    float* out = (float*)d_out;

    hipLaunchKernelGGL(st_kernel, dim3(BATCH), dim3(256), 0, stream,
                       state, inputs, bias, diag, out);
}

// Round 8
// 25.096 us; speedup vs baseline: 1.2037x; 1.2037x over previous
//
#include <hip/hip_runtime.h>
#include <math.h>

#define NH    16384   // Hadamard size (2^14)
#define NRES  8192
#define NINP  64
#define BATCH 512

typedef float v2f __attribute__((ext_vector_type(2)));

// ---------------- LDS swizzle (rank-3 lane->quadbank for all layouts) ------
__device__ __forceinline__ constexpr int gfold(int v) {
    return ((v >> 5) & 7) ^ ((v >> 8) & 7) ^ ((v >> 11) & 7);
}
__device__ __forceinline__ constexpr int physf(int v) {
    return v ^ (gfold(v) << 2);
}

// ---------------- packed FWHT stages ---------------------------------------
// X[32] packs; scalar element f (0..63) = X[f>>1][f&1]. f bits: {0}=in-pack,
// {1}=pack parity, {2-5}=pack bits 1-4 (the "j" register bits).
template <int T>
__device__ __forceinline__ void pstage(v2f X[32]) {
#pragma unroll
    for (int p = 0; p < 32; ++p) {
        if (!(p & T)) {
            v2f A = X[p], B = X[p | T];
            X[p]     = A + B;     // v_pk_add_f32
            X[p | T] = A - B;     // v_pk_add_f32 (neg)
        }
    }
}
// idx-bit-0 stage: within-pack butterfly
__device__ __forceinline__ void vstage0(v2f X[32]) {
#pragma unroll
    for (int p = 0; p < 32; ++p) {
        float a = X[p].x, b = X[p].y;
        X[p].x = a + b;
        X[p].y = a - b;
    }
}

// ---------------- cross-lane primitives ------------------------------------
template <int CTRL>
__device__ __forceinline__ float dppf(float v) {
    return __builtin_bit_cast(float,
        __builtin_amdgcn_update_dpp(0, __builtin_bit_cast(int, v), CTRL, 0xF, 0xF, true));
}
// value-in/value-out swap of a lane-pair across register pair (A,B)
template <int CTRL>
__device__ __forceinline__ void dpp_swap(float A, float B, bool odd, float& oA, float& oB) {
    float dA = dppf<CTRL>(A), dB = dppf<CTRL>(B);
    oA = odd ? dB : A;
    oB = odd ? B  : dA;
}
__device__ __forceinline__ void pl16_swap(float& a, float& b) {
    asm("v_permlane16_swap_b32 %0, %1" : "+v"(a), "+v"(b));
}
__device__ __forceinline__ void pl32_swap(float& a, float& b) {
    asm("v_permlane32_swap_b32 %0, %1" : "+v"(a), "+v"(b));
}

// Shuffle-exchange: swap register j-bits with lane bits, pure VALU pipe.
//   j0(pack bit1) <-> l0 : DPP quad_perm xor1 (0xB1)
//   j1(pack bit2) <-> l1 : DPP quad_perm xor2 (0x4E)
//   j2(pack bit3) <-> l4 : v_permlane16_swap_b32
//   j3(pack bit4) <-> l5 : v_permlane32_swap_b32
__device__ __forceinline__ void shuffle_exchange(v2f X[32], bool odd0, bool odd1) {
#pragma unroll
    for (int p = 0; p < 32; ++p) if (!(p & 2)) {          // j0 <-> l0
        float a0, a1, b0, b1;
        dpp_swap<0xB1>(X[p].x, X[p | 2].x, odd0, a0, b0);
        dpp_swap<0xB1>(X[p].y, X[p | 2].y, odd0, a1, b1);
        X[p] = (v2f){a0, a1}; X[p | 2] = (v2f){b0, b1};
    }
#pragma unroll
    for (int p = 0; p < 32; ++p) if (!(p & 4)) {          // j1 <-> l1
        float a0, a1, b0, b1;
        dpp_swap<0x4E>(X[p].x, X[p | 4].x, odd1, a0, b0);
        dpp_swap<0x4E>(X[p].y, X[p | 4].y, odd1, a1, b1);
        X[p] = (v2f){a0, a1}; X[p | 4] = (v2f){b0, b1};
    }
#pragma unroll
    for (int p = 0; p < 32; ++p) if (!(p & 8)) {          // j2 <-> l4
        float a = X[p].x, b = X[p | 8].x; pl16_swap(a, b); X[p].x = a; X[p | 8].x = b;
        float c = X[p].y, d = X[p | 8].y; pl16_swap(c, d); X[p].y = c; X[p | 8].y = d;
    }
#pragma unroll
    for (int p = 0; p < 32; ++p) if (!(p & 16)) {         // j3 <-> l5
        float a = X[p].x, b = X[p | 16].x; pl32_swap(a, b); X[p].x = a; X[p | 16].x = b;
        float c = X[p].y, d = X[p | 16].y; pl32_swap(c, d); X[p].y = c; X[p | 16].y = d;
    }
}

// ---------------- LDS exchange helpers -------------------------------------
#define WRX(Q, SH) do { _Pragma("unroll") \
    for (int j = 0; j < 16; ++j) \
        lds4[(unsigned)((Q) ^ physf(j << (SH))) >> 2] = \
            make_float4(X[2*j].x, X[2*j].y, X[2*j+1].x, X[2*j+1].y); } while (0)

#define RDX(Q, SH) do { _Pragma("unroll") \
    for (int j = 0; j < 16; ++j) { \
        float4 v = lds4[(unsigned)((Q) ^ physf(j << (SH))) >> 2]; \
        X[2*j]   = (v2f){v.x, v.y}; \
        X[2*j+1] = (v2f){v.z, v.w}; } } while (0)

// Diag multiply in two 8-wide chunks (bounded register liveness).
#define DIAG_MUL(BASEPTR, SH) do { \
    _Pragma("unroll") for (int h = 0; h < 2; ++h) { \
        float4 dv[8]; \
        _Pragma("unroll") for (int k = 0; k < 8; ++k) \
            dv[k] = *(const float4*)((BASEPTR) + ((h * 8 + k) << (SH))); \
        _Pragma("unroll") for (int k = 0; k < 8; ++k) { \
            const int j = h * 8 + k; \
            X[2*j]   *= (v2f){dv[k].x, dv[k].y}; \
            X[2*j+1] *= (v2f){dv[k].z, dv[k].w}; \
        } \
    } } while (0)

// Fast erf: erf(z) ~ tanh(z*(1.1283793 + 0.10090*z^2)), max err ~1e-3.
__device__ __forceinline__ float erf_fast(float z) {
    float p = z * z;
    float u = z * fmaf(p, 0.10090f, 1.1283793f);
    float e = __builtin_amdgcn_exp2f(u * 2.8853902f);   // e^(2u)
    float r = __builtin_amdgcn_rcpf(e + 1.0f);
    return fmaf(-2.0f, r, 1.0f);                        // 1 - 2/(e^(2u)+1)
}

// Layouts (idx bit homes; v=idx{0,1} in-register, j = 4 register bits,
// la={l0,l1}, lb={l4,l5}, lc={l2,l3}, w = wave bits):
//  T_A: j@{2-5}, la@{6,7}, lb@{8,9}, lc@{10,11}, w@{12,13}
//  T_B: j@{6-9}, la@{2,3}, lb@{4,5}, lc@{10,11}, w@{12,13}
//  T_C: j@{10-13}, la@{2,3}, lb@{4,5}, lc@{6,7}, w@{8,9}
//  T_D: j@{2-5},  lc@{6,7}, w@{8,9}, la@{10,11}, lb@{12,13}
// Plan: P1(T_A: L0 {0-5}) -shuf-> P2(T_B: L0 {6-9}) -LDS-> P3(T_C: L0 {10-13},
// diag1, L1 {0,1,10-13}) -shuf-> P4(T_D: L1 {2-5}) -LDS-> P5(T_B: L1 {6-9},
// diag2, L2 {0,1,6-9}) -shuf-> P6(T_A: L2 {2-5}) -LDS-> P7(T_C: L2 {10-13}, out)

__global__ __launch_bounds__(256, 2) void st_kernel(
    const float* __restrict__ state, const float* __restrict__ inputs,
    const float* __restrict__ bias,  const float* __restrict__ diag,
    float* __restrict__ out)
{
    __shared__ float4 lds4[NH / 4];
    const int t = threadIdx.x;   // 0..255
    const int r = blockIdx.x;    // 0..511
    const int l = t & 63, w = t >> 6;
    const int l01 = l & 3, l23 = (l >> 2) & 3, l45 = (l >> 4) & 3;
    const bool odd0 = (l & 1), odd1 = (l & 2);

    const int bA = (w << 12) | (l23 << 10) | (l45 << 8) | (l01 << 6);
    const int bB = (w << 12) | (l23 << 10) | (l45 << 4) | (l01 << 2);
    const int bC = (w << 8)  | (l23 << 6)  | (l45 << 4) | (l01 << 2);
    const int bD = (l45 << 12) | (l01 << 10) | (w << 8) | (l23 << 6);

    v2f X[32];

    // ---------- prologue: load in T_A layout (idx = bA + f, 64 contiguous) --
    if (t < 128) {                       // idx13 = 0 -> state half
        const float* srow = state + (size_t)r * NRES + bA;
        const float* d0   = diag + bA;
#pragma unroll
        for (int h = 0; h < 2; ++h) {
            float4 sv[8], dv[8];
#pragma unroll
            for (int k = 0; k < 8; ++k) {
                sv[k] = *(const float4*)(srow + 4 * (h * 8 + k));
                dv[k] = *(const float4*)(d0   + 4 * (h * 8 + k));
            }
#pragma unroll
            for (int k = 0; k < 8; ++k) {
                const int j = h * 8 + k;
                X[2*j]   = (v2f){0.9f * sv[k].x * dv[k].x, 0.9f * sv[k].y * dv[k].y};
                X[2*j+1] = (v2f){0.9f * sv[k].z * dv[k].z, 0.9f * sv[k].w * dv[k].w};
            }
        }
    } else if (t == 128) {               // bA = 8192 -> inputs (64 floats)
        const float* irow = inputs + r * NINP;
        const float* d0   = diag + NRES;
#pragma unroll
        for (int j = 0; j < 16; ++j) {
            float4 v = *(const float4*)(irow + 4 * j);
            float4 d = *(const float4*)(d0 + 4 * j);
            X[2*j]   = (v2f){0.4f * v.x * d.x, 0.4f * v.y * d.y};
            X[2*j+1] = (v2f){0.4f * v.z * d.z, 0.4f * v.w * d.w};
        }
    } else {
#pragma unroll
        for (int p = 0; p < 32; ++p) X[p] = (v2f){0.f, 0.f};
    }

    // ---------- P1 (T_A): layer0 bits 0-5 ----------
    vstage0(X); pstage<1>(X); pstage<2>(X);
    pstage<4>(X); pstage<8>(X); pstage<16>(X);

    // ---------- E1 (shuffle): T_A -> T_B ----------
    shuffle_exchange(X, odd0, odd1);
    pstage<2>(X); pstage<4>(X); pstage<8>(X); pstage<16>(X);     // L0 6-9

    // ---------- E2 (LDS): T_B -> T_C ----------
    { const int Q = physf(bB); WRX(Q, 6); }
    __syncthreads();
    { const int Q = physf(bC); RDX(Q, 10); }
    pstage<2>(X); pstage<4>(X); pstage<8>(X); pstage<16>(X);     // L0 10-13
    DIAG_MUL(diag + NH + bC, 10);                                 // diag1
    vstage0(X); pstage<1>(X);                                     // L1 0-1
    pstage<2>(X); pstage<4>(X); pstage<8>(X); pstage<16>(X);     // L1 10-13

    // ---------- E3 (shuffle): T_C -> T_D ----------
    shuffle_exchange(X, odd0, odd1);
    pstage<2>(X); pstage<4>(X); pstage<8>(X); pstage<16>(X);     // L1 2-5

    // ---------- E4 (LDS): T_D -> T_B ----------
    __syncthreads();                     // protect buffer from E2 reads
    { const int Q = physf(bD); WRX(Q, 2); }
    __syncthreads();
    { const int Q = physf(bB); RDX(Q, 6); }
    pstage<2>(X); pstage<4>(X); pstage<8>(X); pstage<16>(X);     // L1 6-9
    DIAG_MUL(diag + 2 * NH + bB, 6);                              // diag2
    vstage0(X); pstage<1>(X);                                     // L2 0-1
    pstage<2>(X); pstage<4>(X); pstage<8>(X); pstage<16>(X);     // L2 6-9

    // ---------- E5 (shuffle): T_B -> T_A ----------
    shuffle_exchange(X, odd0, odd1);
    pstage<2>(X); pstage<4>(X); pstage<8>(X); pstage<16>(X);     // L2 2-5

    // ---------- E6 (LDS): T_A -> T_C ----------
    __syncthreads();                     // protect buffer from E4 reads
    { const int Q = physf(bA); WRX(Q, 2); }
    __syncthreads();
    { const int Q = physf(bC); RDX(Q, 10); }
    pstage<2>(X); pstage<4>(X); pstage<8>(X); pstage<16>(X);     // L2 10-13

    // ---------- epilogue: idx13 = j3 = 0 -> j < 8 ----------
    {
        float* orow = out + (size_t)r * NRES;
        const float inv = 1.0f / (float)NH;
#pragma unroll
        for (int j = 0; j < 8; ++j) {
            float4 b = *(const float4*)(bias + bC + (j << 10));
            float4 o;
            o.x = erf_fast(fmaf(X[2*j].x,   inv, b.x));
            o.y = erf_fast(fmaf(X[2*j].y,   inv, b.y));
            o.z = erf_fast(fmaf(X[2*j+1].x, inv, b.z));
            o.w = erf_fast(fmaf(X[2*j+1].y, inv, b.w));
            *(float4*)(orow + bC + (j << 10)) = o;
        }
    }
}

extern "C" void kernel_launch(void* const* d_in, const int* in_sizes, int n_in,
                              void* d_out, int out_size, void* d_ws, size_t ws_size,
                              hipStream_t stream) {
    (void)in_sizes; (void)n_in; (void)out_size; (void)d_ws; (void)ws_size;
    const float* state  = (const float*)d_in[0];
    const float* inputs = (const float*)d_in[1];
    const float* bias   = (const float*)d_in[2];
    const float* diag   = (const float*)d_in[3];
    float* out = (float*)d_out;

    hipLaunchKernelGGL(st_kernel, dim3(BATCH), dim3(256), 0, stream,
                       state, inputs, bias, diag, out);
}

// Round 9
// 24.677 us; speedup vs baseline: 1.2242x; 1.0170x over previous
//
#include <hip/hip_runtime.h>
#include <math.h>

#define NH    16384   // Hadamard size (2^14)
#define NRES  8192
#define NINP  64
#define BATCH 512

typedef float v2f __attribute__((ext_vector_type(2)));

// ---------------- LDS swizzle (rank-3 lane->quadbank for all layouts) ------
__device__ __forceinline__ constexpr int gfold(int v) {
    return ((v >> 5) & 7) ^ ((v >> 8) & 7) ^ ((v >> 11) & 7);
}
__device__ __forceinline__ constexpr int physf(int v) {
    return v ^ (gfold(v) << 2);
}

// ---------------- packed butterfly primitives (forced v_pk_*) --------------
__device__ __forceinline__ v2f pk_add(v2f a, v2f b) {
    v2f d;
    asm("v_pk_add_f32 %0, %1, %2" : "=v"(d) : "v"(a), "v"(b));
    return d;
}
// a - b  ==  fma(b, -1, a)   (exact, single rounding)
__device__ __forceinline__ v2f pk_sub(v2f a, v2f b, v2f negone) {
    v2f d;
    asm("v_pk_fma_f32 %0, %1, %2, %3" : "=v"(d) : "v"(b), "v"(negone), "v"(a));
    return d;
}

// ---------------- packed FWHT stages ---------------------------------------
// X[32] packs; scalar element f (0..63) = X[f>>1][f&1]. f bits: {0}=in-pack,
// {1}=pack parity, {2-5}=pack bits 1-4 (the "j" register bits).
template <int T>
__device__ __forceinline__ void pstage(v2f X[32], v2f negone) {
#pragma unroll
    for (int p = 0; p < 32; ++p) {
        if (!(p & T)) {
            v2f A = X[p], B = X[p | T];
            X[p]     = pk_add(A, B);
            X[p | T] = pk_sub(A, B, negone);
        }
    }
}
// idx-bit-0 stage: within-pack butterfly
__device__ __forceinline__ void vstage0(v2f X[32]) {
#pragma unroll
    for (int p = 0; p < 32; ++p) {
        float a = X[p].x, b = X[p].y;
        X[p].x = a + b;
        X[p].y = a - b;
    }
}

// ---------------- cross-lane primitives ------------------------------------
template <int CTRL>
__device__ __forceinline__ float dppf(float v) {
    return __builtin_bit_cast(float,
        __builtin_amdgcn_update_dpp(0, __builtin_bit_cast(int, v), CTRL, 0xF, 0xF, true));
}
// value-in/value-out swap of a lane-pair across register pair (A,B)
template <int CTRL>
__device__ __forceinline__ void dpp_swap(float A, float B, bool odd, float& oA, float& oB) {
    float dA = dppf<CTRL>(A), dB = dppf<CTRL>(B);
    oA = odd ? dB : A;
    oB = odd ? B  : dA;
}
__device__ __forceinline__ void pl16_swap(float& a, float& b) {
    asm("v_permlane16_swap_b32 %0, %1" : "+v"(a), "+v"(b));
}
__device__ __forceinline__ void pl32_swap(float& a, float& b) {
    asm("v_permlane32_swap_b32 %0, %1" : "+v"(a), "+v"(b));
}

// Shuffle-exchange: swap register j-bits with lane bits, pure VALU pipe.
//   j0(pack bit1) <-> l0 : DPP quad_perm xor1 (0xB1)
//   j1(pack bit2) <-> l1 : DPP quad_perm xor2 (0x4E)
//   j2(pack bit3) <-> l4 : v_permlane16_swap_b32
//   j3(pack bit4) <-> l5 : v_permlane32_swap_b32
__device__ __forceinline__ void shuffle_exchange(v2f X[32], bool odd0, bool odd1) {
#pragma unroll
    for (int p = 0; p < 32; ++p) if (!(p & 2)) {          // j0 <-> l0
        float a0, a1, b0, b1;
        dpp_swap<0xB1>(X[p].x, X[p | 2].x, odd0, a0, b0);
        dpp_swap<0xB1>(X[p].y, X[p | 2].y, odd0, a1, b1);
        X[p] = (v2f){a0, a1}; X[p | 2] = (v2f){b0, b1};
    }
#pragma unroll
    for (int p = 0; p < 32; ++p) if (!(p & 4)) {          // j1 <-> l1
        float a0, a1, b0, b1;
        dpp_swap<0x4E>(X[p].x, X[p | 4].x, odd1, a0, b0);
        dpp_swap<0x4E>(X[p].y, X[p | 4].y, odd1, a1, b1);
        X[p] = (v2f){a0, a1}; X[p | 4] = (v2f){b0, b1};
    }
#pragma unroll
    for (int p = 0; p < 32; ++p) if (!(p & 8)) {          // j2 <-> l4
        float a = X[p].x, b = X[p | 8].x; pl16_swap(a, b); X[p].x = a; X[p | 8].x = b;
        float c = X[p].y, d = X[p | 8].y; pl16_swap(c, d); X[p].y = c; X[p | 8].y = d;
    }
#pragma unroll
    for (int p = 0; p < 32; ++p) if (!(p & 16)) {         // j3 <-> l5
        float a = X[p].x, b = X[p | 16].x; pl32_swap(a, b); X[p].x = a; X[p | 16].x = b;
        float c = X[p].y, d = X[p | 16].y; pl32_swap(c, d); X[p].y = c; X[p | 16].y = d;
    }
}

// ---------------- LDS exchange helpers -------------------------------------
#define WRX(Q, SH) do { _Pragma("unroll") \
    for (int j = 0; j < 16; ++j) \
        lds4[(unsigned)((Q) ^ physf(j << (SH))) >> 2] = \
            make_float4(X[2*j].x, X[2*j].y, X[2*j+1].x, X[2*j+1].y); } while (0)

#define RDX(Q, SH) do { _Pragma("unroll") \
    for (int j = 0; j < 16; ++j) { \
        float4 v = lds4[(unsigned)((Q) ^ physf(j << (SH))) >> 2]; \
        X[2*j]   = (v2f){v.x, v.y}; \
        X[2*j+1] = (v2f){v.z, v.w}; } } while (0)

// Apply a prefetched diag (16 float4) to X.
#define DIAG_APPLY(PF) do { _Pragma("unroll") \
    for (int j = 0; j < 16; ++j) { \
        X[2*j]   *= (v2f){(PF)[j].x, (PF)[j].y}; \
        X[2*j+1] *= (v2f){(PF)[j].z, (PF)[j].w}; \
    } } while (0)

// Fast erf: erf(z) ~ tanh(z*(1.1283793 + 0.10090*z^2)), max err ~1e-3.
__device__ __forceinline__ float erf_fast(float z) {
    float p = z * z;
    float u = z * fmaf(p, 0.10090f, 1.1283793f);
    float e = __builtin_amdgcn_exp2f(u * 2.8853902f);   // e^(2u)
    float r = __builtin_amdgcn_rcpf(e + 1.0f);
    return fmaf(-2.0f, r, 1.0f);                        // 1 - 2/(e^(2u)+1)
}

// Layouts (idx bit homes; v=idx{0,1} in-register, j = 4 register bits,
// la={l0,l1}, lb={l4,l5}, lc={l2,l3}, w = wave bits):
//  T_A: j@{2-5}, la@{6,7}, lb@{8,9}, lc@{10,11}, w@{12,13}
//  T_B: j@{6-9}, la@{2,3}, lb@{4,5}, lc@{10,11}, w@{12,13}
//  T_C: j@{10-13}, la@{2,3}, lb@{4,5}, lc@{6,7}, w@{8,9}
//  T_D: j@{2-5},  lc@{6,7}, w@{8,9}, la@{10,11}, lb@{12,13}
// Plan: P1(T_A: L0 {0-5}) -shuf-> P2(T_B: L0 {6-9}) -LDS-> P3(T_C: L0 {10-13},
// diag1, L1 {0,1,10-13}) -shuf-> P4(T_D: L1 {2-5}) -LDS-> P5(T_B: L1 {6-9},
// diag2, L2 {0,1,6-9}) -shuf-> P6(T_A: L2 {2-5}) -LDS-> P7(T_C: L2 {10-13}, out)

__global__ __launch_bounds__(256, 2) void st_kernel(
    const float* __restrict__ state, const float* __restrict__ inputs,
    const float* __restrict__ bias,  const float* __restrict__ diag,
    float* __restrict__ out)
{
    __shared__ float4 lds4[NH / 4];
    const int t = threadIdx.x;   // 0..255
    const int r = blockIdx.x;    // 0..511
    const int l = t & 63, w = t >> 6;
    const int l01 = l & 3, l23 = (l >> 2) & 3, l45 = (l >> 4) & 3;
    const bool odd0 = (l & 1), odd1 = (l & 2);

    const int bA = (w << 12) | (l23 << 10) | (l45 << 8) | (l01 << 6);
    const int bB = (w << 12) | (l23 << 10) | (l45 << 4) | (l01 << 2);
    const int bC = (w << 8)  | (l23 << 6)  | (l45 << 4) | (l01 << 2);
    const int bD = (l45 << 12) | (l01 << 10) | (w << 8) | (l23 << 6);

    const v2f negone = (v2f){-1.0f, -1.0f};

    v2f X[32];

    // ---------- prologue: load in T_A layout (idx = bA + f, 64 contiguous) --
    if (t < 128) {                       // idx13 = 0 -> state half
        const float* srow = state + (size_t)r * NRES + bA;
        const float* d0   = diag + bA;
#pragma unroll
        for (int h = 0; h < 2; ++h) {
            float4 sv[8], dv[8];
#pragma unroll
            for (int k = 0; k < 8; ++k) {
                sv[k] = *(const float4*)(srow + 4 * (h * 8 + k));
                dv[k] = *(const float4*)(d0   + 4 * (h * 8 + k));
            }
#pragma unroll
            for (int k = 0; k < 8; ++k) {
                const int j = h * 8 + k;
                X[2*j]   = (v2f){0.9f * sv[k].x * dv[k].x, 0.9f * sv[k].y * dv[k].y};
                X[2*j+1] = (v2f){0.9f * sv[k].z * dv[k].z, 0.9f * sv[k].w * dv[k].w};
            }
        }
    } else if (t == 128) {               // bA = 8192 -> inputs (64 floats)
        const float* irow = inputs + r * NINP;
        const float* d0   = diag + NRES;
#pragma unroll
        for (int j = 0; j < 16; ++j) {
            float4 v = *(const float4*)(irow + 4 * j);
            float4 d = *(const float4*)(d0 + 4 * j);
            X[2*j]   = (v2f){0.4f * v.x * d.x, 0.4f * v.y * d.y};
            X[2*j+1] = (v2f){0.4f * v.z * d.z, 0.4f * v.w * d.w};
        }
    } else {
#pragma unroll
        for (int p = 0; p < 32; ++p) X[p] = (v2f){0.f, 0.f};
    }

    // ---------- P1 (T_A): layer0 bits 0-5 ----------
    vstage0(X); pstage<1>(X, negone); pstage<2>(X, negone);
    pstage<4>(X, negone); pstage<8>(X, negone); pstage<16>(X, negone);

    // ---------- E1 (shuffle): T_A -> T_B ----------
    shuffle_exchange(X, odd0, odd1);
    pstage<2>(X, negone); pstage<4>(X, negone);
    pstage<8>(X, negone); pstage<16>(X, negone);                 // L0 6-9

    // prefetch diag1 (T_C: idx = bC | j<<10 | v) -- consumed after E2's RDX
    float4 pf1[16];
    {
        const float* d1 = diag + NH + bC;
#pragma unroll
        for (int j = 0; j < 16; ++j) pf1[j] = *(const float4*)(d1 + (j << 10));
    }

    // ---------- E2 (LDS): T_B -> T_C ----------
    { const int Q = physf(bB); WRX(Q, 6); }
    __syncthreads();
    { const int Q = physf(bC); RDX(Q, 10); }
    pstage<2>(X, negone); pstage<4>(X, negone);
    pstage<8>(X, negone); pstage<16>(X, negone);                 // L0 10-13
    DIAG_APPLY(pf1);                                              // diag1
    vstage0(X); pstage<1>(X, negone);                             // L1 0-1
    pstage<2>(X, negone); pstage<4>(X, negone);
    pstage<8>(X, negone); pstage<16>(X, negone);                 // L1 10-13

    // ---------- E3 (shuffle): T_C -> T_D ----------
    shuffle_exchange(X, odd0, odd1);
    pstage<2>(X, negone); pstage<4>(X, negone);
    pstage<8>(X, negone); pstage<16>(X, negone);                 // L1 2-5

    // prefetch diag2 (T_B: idx = bB | j<<6 | v) -- consumed after E4's RDX
    float4 pf2[16];
    {
        const float* d2 = diag + 2 * NH + bB;
#pragma unroll
        for (int j = 0; j < 16; ++j) pf2[j] = *(const float4*)(d2 + (j << 6));
    }

    // ---------- E4 (LDS): T_D -> T_B ----------
    __syncthreads();                     // protect buffer from E2 reads
    { const int Q = physf(bD); WRX(Q, 2); }
    __syncthreads();
    { const int Q = physf(bB); RDX(Q, 6); }
    pstage<2>(X, negone); pstage<4>(X, negone);
    pstage<8>(X, negone); pstage<16>(X, negone);                 // L1 6-9
    DIAG_APPLY(pf2);                                              // diag2
    vstage0(X); pstage<1>(X, negone);                             // L2 0-1
    pstage<2>(X, negone); pstage<4>(X, negone);
    pstage<8>(X, negone); pstage<16>(X, negone);                 // L2 6-9

    // ---------- E5 (shuffle): T_B -> T_A ----------
    shuffle_exchange(X, odd0, odd1);
    pstage<2>(X, negone); pstage<4>(X, negone);
    pstage<8>(X, negone); pstage<16>(X, negone);                 // L2 2-5

    // prefetch bias (output half j<8: idx = bC | j<<10 | v) -- consumed in epilogue
    float4 bv[8];
#pragma unroll
    for (int j = 0; j < 8; ++j) bv[j] = *(const float4*)(bias + bC + (j << 10));

    // ---------- E6 (LDS): T_A -> T_C ----------
    __syncthreads();                     // protect buffer from E4 reads
    { const int Q = physf(bA); WRX(Q, 2); }
    __syncthreads();
    { const int Q = physf(bC); RDX(Q, 10); }
    pstage<2>(X, negone); pstage<4>(X, negone);
    pstage<8>(X, negone); pstage<16>(X, negone);                 // L2 10-13

    // ---------- epilogue: idx13 = j3 = 0 -> j < 8 ----------
    {
        float* orow = out + (size_t)r * NRES;
        const float inv = 1.0f / (float)NH;
#pragma unroll
        for (int j = 0; j < 8; ++j) {
            float4 o;
            o.x = erf_fast(fmaf(X[2*j].x,   inv, bv[j].x));
            o.y = erf_fast(fmaf(X[2*j].y,   inv, bv[j].y));
            o.z = erf_fast(fmaf(X[2*j+1].x, inv, bv[j].z));
            o.w = erf_fast(fmaf(X[2*j+1].y, inv, bv[j].w));
            *(float4*)(orow + bC + (j << 10)) = o;
        }
    }
}

extern "C" void kernel_launch(void* const* d_in, const int* in_sizes, int n_in,
                              void* d_out, int out_size, void* d_ws, size_t ws_size,
                              hipStream_t stream) {
    (void)in_sizes; (void)n_in; (void)out_size; (void)d_ws; (void)ws_size;
    const float* state  = (const float*)d_in[0];
    const float* inputs = (const float*)d_in[1];
    const float* bias   = (const float*)d_in[2];
    const float* diag   = (const float*)d_in[3];
    float* out = (float*)d_out;

    hipLaunchKernelGGL(st_kernel, dim3(BATCH), dim3(256), 0, stream,
                       state, inputs, bias, diag, out);
}